// Round 9
// baseline (234.539 us; speedup 1.0000x reference)
//
#include <hip/hip_runtime.h>
#include <math.h>

#define T_SEQ     2048
#define HIDDEN_   2048
#define NUM_HEADS 16
#define NUM_KV    8
#define HEAD_DIM  128
#define Q_SIZE    2048
#define KV_SIZE   1024
#define QKV_N     4096
#define QK_N      3072
#define EPS_      1e-6f

typedef __attribute__((ext_vector_type(8))) short short8;
typedef __attribute__((ext_vector_type(4))) float floatx4;

__device__ __forceinline__ unsigned short f2bf(float f) {
    unsigned int u = __float_as_uint(f);
    u += 0x7fffu + ((u >> 16) & 1u);     // RNE
    return (unsigned short)(u >> 16);
}
__device__ __forceinline__ float b2f(unsigned short u) {
    return __uint_as_float((unsigned int)u << 16);
}

__device__ __forceinline__ void stage16(const unsigned short* g, unsigned short* lds_base) {
    __builtin_amdgcn_global_load_lds(
        (const __attribute__((address_space(1))) unsigned int*)g,
        (__attribute__((address_space(3))) unsigned int*)lds_base, 16, 0, 0);
}

// ---------------------------------------------------------------------------
// Fused fp32 -> bf16 conversion of hidden, qkv_w, o_w in ONE launch.
// ---------------------------------------------------------------------------
#define H4 (T_SEQ * HIDDEN_ / 4)
#define W4 (QKV_N * HIDDEN_ / 4)
#define O4 (Q_SIZE * HIDDEN_ / 4)

__global__ __launch_bounds__(256) void convert_all(
    const float* __restrict__ hidden, const float* __restrict__ qkv_w,
    const float* __restrict__ o_w, unsigned short* __restrict__ hbf,
    unsigned short* __restrict__ wbf, unsigned short* __restrict__ obf)
{
    int i = blockIdx.x * 256 + threadIdx.x;
    const float4* src;
    ushort4* dst;
    int j;
    if (i < H4)            { src = (const float4*)hidden; dst = (ushort4*)hbf; j = i; }
    else if (i < H4 + W4)  { src = (const float4*)qkv_w;  dst = (ushort4*)wbf; j = i - H4; }
    else                   { src = (const float4*)o_w;    dst = (ushort4*)obf; j = i - H4 - W4;
                             if (j >= O4) return; }
    float4 v = src[j];
    ushort4 o;
    o.x = f2bf(v.x); o.y = f2bf(v.y); o.z = f2bf(v.z); o.w = f2bf(v.w);
    dst[j] = o;
}

// ---------------------------------------------------------------------------
// bf16 MFMA GEMM (NT), 128x128 tile, 1024 threads / 16 waves, wave-tile 32x32.
// Counted-vmcnt pipeline (BK=64, dbuf, raw s_barrier, never vmcnt(0)
// mid-loop). Used for QKV only (MODE 1) as of R17 — the O-projection moved
// to the dedicated gemm_o below (its 256-block grid left it at 4 waves/SIMD,
// half QKV's TLP, and it ran at half QKV's FLOP rate).
// MODE 1 (QKV): q/k: fused RMSNorm + RoPE epilogue; v: transposed Vt store.
// ---------------------------------------------------------------------------
template<int MODE>
__global__ __launch_bounds__(1024, 8) void gemm_nt_bf16(
    const unsigned short* __restrict__ A, const unsigned short* __restrict__ B,
    float* __restrict__ C,
    unsigned short* __restrict__ Qb, unsigned short* __restrict__ Kb,
    unsigned short* __restrict__ Vt,
    const int* __restrict__ positions,
    const float* __restrict__ qw, const float* __restrict__ kw,
    int M, int N, int K)
{
    // smem: As[2][128*64] at 0, Bs[2][128*64] at 16384 (elem offsets). 64 KB.
    __shared__ unsigned short smem[32768];
    unsigned short* const As0 = smem;
    unsigned short* const Bs0 = smem + 16384;

    const int tid  = threadIdx.x;
    const int w    = tid >> 6;           // 0..15
    const int lane = tid & 63;
    const int colL = lane & 15;
    const int quad = lane >> 4;
    const int bm = blockIdx.y * 128;
    const int bn = blockIdx.x * 128;
    const int wr = w >> 2;               // 4 row-groups
    const int wc = w & 3;                // 4 col-groups
    const int wm = wr * 32;
    const int wn = wc * 32;

    floatx4 acc[2][2];
    #pragma unroll
    for (int i = 0; i < 2; ++i)
        #pragma unroll
        for (int j = 0; j < 2; ++j)
            acc[i][j] = (floatx4){0.f, 0.f, 0.f, 0.f};

    // 1024 16B-chunks per matrix per tile; 1024 threads -> 1 chunk each.
    const int s_r  = tid >> 3;
    const int s_lc = (tid & 7) ^ (s_r & 7);

    auto stage_tile = [&](int buf, int k0) {
        stage16(A + (size_t)(bm + s_r) * K + k0 + s_lc * 8,
                As0 + buf * 8192 + tid * 8);
        stage16(B + (size_t)(bn + s_r) * K + k0 + s_lc * 8,
                Bs0 + buf * 8192 + tid * 8);
    };

    const int nt = K >> 6;          // K/64 tiles
    stage_tile(0, 0);               // prologue: 2 loads/thread in flight

    for (int t = 0; t < nt; ++t) {
        const int b = t & 1;
        if (t + 1 < nt) {
            stage_tile(b ^ 1, (t + 1) << 6);              // 2 more in flight
            asm volatile("s_waitcnt vmcnt(2)" ::: "memory"); // tile t ready
        } else {
            asm volatile("s_waitcnt vmcnt(0)" ::: "memory");
        }
        __builtin_amdgcn_s_barrier();        // raw: no vmcnt drain
        __builtin_amdgcn_sched_barrier(0);

        const unsigned short* la = As0 + b * 8192;
        const unsigned short* lb = Bs0 + b * 8192;
        #pragma unroll
        for (int kk = 0; kk < 2; ++kk) {
            short8 af[2], bfv[2];
            #pragma unroll
            for (int i = 0; i < 2; ++i) {
                int ra = wm + i * 16 + colL;
                af[i]  = *(const short8*)&la[ra * 64 + (((kk * 4 + quad) ^ (ra & 7)) * 8)];
            }
            #pragma unroll
            for (int j = 0; j < 2; ++j) {
                int rb = wn + j * 16 + colL;
                bfv[j] = *(const short8*)&lb[rb * 64 + (((kk * 4 + quad) ^ (rb & 7)) * 8)];
            }
            #pragma unroll
            for (int i = 0; i < 2; ++i)
                #pragma unroll
                for (int j = 0; j < 2; ++j)
                    acc[i][j] = __builtin_amdgcn_mfma_f32_16x16x32_bf16(af[i], bfv[j], acc[i][j], 0, 0, 0);
        }
        __builtin_amdgcn_sched_barrier(0);
        asm volatile("" ::: "memory");
        __builtin_amdgcn_s_barrier();        // all reads of buf b done before overwrite
    }

    if constexpr (MODE == 0) {
        #pragma unroll
        for (int i = 0; i < 2; ++i)
            #pragma unroll
            for (int j = 0; j < 2; ++j)
                #pragma unroll
                for (int rr = 0; rr < 4; ++rr) {
                    int row = bm + wm + i * 16 + quad * 4 + rr;
                    int cc2 = bn + wn + j * 16 + colL;
                    C[(size_t)row * N + cc2] = acc[i][j][rr];
                }
    } else {
        if (bn < QK_N) {
            // ---------- Phase A: RMSNorm, acc -> bf16 xnL, acc dies ----------
            __shared__ float sums[4][128];
            unsigned short* xnL = smem;     // overlay: [d][row], stride 132

            float p[2][4];
            #pragma unroll
            for (int i = 0; i < 2; ++i)
                #pragma unroll
                for (int rr = 0; rr < 4; ++rr) {
                    float sv = 0.f;
                    #pragma unroll
                    for (int j = 0; j < 2; ++j)
                        sv = fmaf(acc[i][j][rr], acc[i][j][rr], sv);
                    p[i][rr] = sv;
                }
            #pragma unroll
            for (int off = 1; off < 16; off <<= 1)
                #pragma unroll
                for (int i = 0; i < 2; ++i)
                    #pragma unroll
                    for (int rr = 0; rr < 4; ++rr)
                        p[i][rr] += __shfl_xor(p[i][rr], off, 64);
            if (colL == 0) {
                #pragma unroll
                for (int i = 0; i < 2; ++i)
                    #pragma unroll
                    for (int rr = 0; rr < 4; ++rr)
                        sums[wc][wm + i * 16 + quad * 4 + rr] = p[i][rr];
            }
            __syncthreads();

            float inv_r[2][4];
            #pragma unroll
            for (int i = 0; i < 2; ++i)
                #pragma unroll
                for (int rr = 0; rr < 4; ++rr) {
                    int row = wm + i * 16 + quad * 4 + rr;
                    float tot = (sums[0][row] + sums[1][row]) + (sums[2][row] + sums[3][row]);
                    inv_r[i][rr] = rsqrtf(tot * (1.0f / HEAD_DIM) + EPS_);
                }

            const float* nw = (bn < Q_SIZE) ? qw : kw;
            float wv[2];
            #pragma unroll
            for (int j = 0; j < 2; ++j)
                wv[j] = nw[wn + j * 16 + colL];

            #pragma unroll
            for (int i = 0; i < 2; ++i)
                #pragma unroll
                for (int j = 0; j < 2; ++j) {
                    ushort4 pk;
                    pk.x = f2bf(acc[i][j][0] * inv_r[i][0] * wv[j]);
                    pk.y = f2bf(acc[i][j][1] * inv_r[i][1] * wv[j]);
                    pk.z = f2bf(acc[i][j][2] * inv_r[i][2] * wv[j]);
                    pk.w = f2bf(acc[i][j][3] * inv_r[i][3] * wv[j]);
                    int d = wn + j * 16 + colL;
                    *(ushort4*)&xnL[d * 132 + wm + i * 16 + quad * 4] = pk;
                }
            __syncthreads();
            // ---------- Phase B: RoPE from LDS only (no acc liveness) ----------
            // 1024 threads: thread -> (row r = tid>>3, freq octant oct = tid&7);
            // 8 sincos/thread, each produces BOTH d and d+64; ushort4 stores.
            {
                const int r = tid >> 3;
                const int oct = tid & 7;
                const float pos = (float)positions[bm + r];
                const bool is_q = (bn < Q_SIZE);
                const float l2r = 13.287712379549449f / 64.0f;
                const float sc = 0.08838834764831845f;
                unsigned short* rowp;
                if (is_q) rowp = Qb + (size_t)(bm + r) * Q_SIZE + (bn >> 7) * HEAD_DIM;
                else      rowp = Kb + ((size_t)((bn - Q_SIZE) >> 7) * T_SEQ + bm + r) * HEAD_DIM;

                #pragma unroll
                for (int f4 = 0; f4 < 8; f4 += 4) {
                    ushort4 lo, hi;
                    #pragma unroll
                    for (int e = 0; e < 4; ++e) {
                        int f = oct * 8 + f4 + e;
                        float x1 = b2f(xnL[f * 132 + r]);          // d = f
                        float x2 = b2f(xnL[(f + 64) * 132 + r]);   // d = f+64
                        float sv, cv;
                        __sincosf(pos * exp2f(-(float)f * l2r), &sv, &cv);
                        float olo = fmaf(x1, cv, -x2 * sv);
                        float ohi = fmaf(x2, cv,  x1 * sv);
                        if (is_q) { olo *= sc; ohi *= sc; }
                        ((unsigned short*)&lo)[e] = f2bf(olo);
                        ((unsigned short*)&hi)[e] = f2bf(ohi);
                    }
                    *(ushort4*)(rowp + oct * 8 + f4)      = lo;
                    *(ushort4*)(rowp + 64 + oct * 8 + f4) = hi;
                }
            }
        } else {
            const int kvh = (bn - QK_N) >> 7;
            #pragma unroll
            for (int i = 0; i < 2; ++i)
                #pragma unroll
                for (int j = 0; j < 2; ++j) {
                    int d = wn + j * 16 + colL;
                    int tok = bm + wm + i * 16 + quad * 4;
                    ushort4 o;
                    o.x = f2bf(acc[i][j][0]); o.y = f2bf(acc[i][j][1]);
                    o.z = f2bf(acc[i][j][2]); o.w = f2bf(acc[i][j][3]);
                    *(ushort4*)&Vt[((size_t)kvh * HEAD_DIM + d) * T_SEQ + tok] = o;
                }
        }
    }
}

// ---------------------------------------------------------------------------
// R17: dedicated O-projection GEMM. 64x64 tile, 512 threads / 8 waves
// (wave-tile 16x32, acc[2]), LDS 32 KB dbuf, same counted-vmcnt pipeline.
// Grid 32x32 = 1024 blocks -> 4 blocks/CU x 8 waves = 32 waves/CU =
// 8 waves/SIMD (HW max), ONE generation, 4 independent blocks per CU
// (vs the old 256-block 128x128 config: 1 block/CU, 4 waves/SIMD,
// barrier-coupled). Working set (16+8 MB) is L3-resident so the halved
// arithmetic intensity costs L2 traffic only.
// ---------------------------------------------------------------------------
__global__ __launch_bounds__(512, 8) void gemm_o(
    const unsigned short* __restrict__ A, const unsigned short* __restrict__ B,
    float* __restrict__ C, int M, int N, int K)
{
    __shared__ unsigned short smem[16384];   // As[2][64*64] + Bs[2][64*64], 32 KB
    unsigned short* const As0 = smem;
    unsigned short* const Bs0 = smem + 8192;

    const int tid  = threadIdx.x;
    const int w    = tid >> 6;           // 0..7
    const int lane = tid & 63;
    const int colL = lane & 15;
    const int quad = lane >> 4;
    const int bm = blockIdx.y * 64;
    const int bn = blockIdx.x * 64;
    const int wm = (w >> 1) * 16;        // 4 row-groups of 16
    const int wn = (w & 1) * 32;         // 2 col-groups of 32

    floatx4 acc[2];
    acc[0] = (floatx4){0.f, 0.f, 0.f, 0.f};
    acc[1] = (floatx4){0.f, 0.f, 0.f, 0.f};

    // 512 16B-chunks per matrix per tile; 512 threads -> 1 chunk each.
    const int s_r  = tid >> 3;
    const int s_lc = (tid & 7) ^ (s_r & 7);

    auto stage_tile = [&](int buf, int k0) {
        stage16(A + (size_t)(bm + s_r) * K + k0 + s_lc * 8,
                As0 + buf * 4096 + tid * 8);
        stage16(B + (size_t)(bn + s_r) * K + k0 + s_lc * 8,
                Bs0 + buf * 4096 + tid * 8);
    };

    const int nt = K >> 6;          // 32 tiles
    stage_tile(0, 0);

    for (int t = 0; t < nt; ++t) {
        const int b = t & 1;
        if (t + 1 < nt) {
            stage_tile(b ^ 1, (t + 1) << 6);
            asm volatile("s_waitcnt vmcnt(2)" ::: "memory");
        } else {
            asm volatile("s_waitcnt vmcnt(0)" ::: "memory");
        }
        __builtin_amdgcn_s_barrier();
        __builtin_amdgcn_sched_barrier(0);

        const unsigned short* la = As0 + b * 4096;
        const unsigned short* lb = Bs0 + b * 4096;
        #pragma unroll
        for (int kk = 0; kk < 2; ++kk) {
            const int ra = wm + colL;
            short8 af = *(const short8*)&la[ra * 64 + (((kk * 4 + quad) ^ (ra & 7)) * 8)];
            #pragma unroll
            for (int j = 0; j < 2; ++j) {
                int rb = wn + j * 16 + colL;
                short8 bfv = *(const short8*)&lb[rb * 64 + (((kk * 4 + quad) ^ (rb & 7)) * 8)];
                acc[j] = __builtin_amdgcn_mfma_f32_16x16x32_bf16(af, bfv, acc[j], 0, 0, 0);
            }
        }
        __builtin_amdgcn_sched_barrier(0);
        asm volatile("" ::: "memory");
        __builtin_amdgcn_s_barrier();
    }

    #pragma unroll
    for (int j = 0; j < 2; ++j)
        #pragma unroll
        for (int rr = 0; rr < 4; ++rr) {
            int row = bm + wm + quad * 4 + rr;
            int col = bn + wn + j * 16 + colL;
            C[(size_t)row * N + col] = acc[j][rr];
        }
}

// ---------------------------------------------------------------------------
// Flash attention, R16 structure (load-balanced 512-token chunks) — unchanged.
// ---------------------------------------------------------------------------
#define BQ 64
#define BK 32

__constant__ unsigned char WORK[80] = {
    124,125,126,127,
    120,121,122,  116,117,118,  112,113,114,  108,109,110,
    104,105,106,  100,101,102,   96, 97, 98,   92, 93, 94,
     88, 89,  84, 85,  80, 81,  76, 77,  72, 73,  68, 69,  64, 65,
     60, 61,
     56, 52, 48, 44, 40, 36, 32,
     28,
    123, 90, 57, 24,
    119, 86, 53, 20,
    115, 82, 49, 16,
    111, 78, 45, 12,
    107, 74, 41,  8,
    103, 70, 37,  4,
     99, 66, 33,  0
};

__device__ __forceinline__ int slot_base(int qt) {
    return (qt < 16) ? (qt - 8) * 2
         : (qt < 24) ? 16 + (qt - 16) * 3
                     : 40 + (qt - 24) * 4;
}

__global__ __launch_bounds__(256) void attn_mfma(
    const unsigned short* __restrict__ Qb, const unsigned short* __restrict__ Kb,
    const unsigned short* __restrict__ Vt, unsigned short* __restrict__ ctxb,
    float* __restrict__ pO1, float* __restrict__ pO2, float* __restrict__ pL)
{
    const int bnum = blockIdx.x;
    const int h = bnum & 15;
    const int enc = WORK[bnum >> 4];
    const int qt = enc >> 2;
    const int ch = enc & 3;
    const int units0 = 2 * (qt + 1) - ch * 16;
    const int units = (units0 < 16) ? units0 : 16;
    const int q0 = qt * BQ;
    const int kv = h >> 1;
    const int tid = threadIdx.x;
    const int w = tid >> 6;
    const int lane = tid & 63;
    const int col = lane & 15;
    const int quad = lane >> 4;

    __shared__ unsigned short Ks[2][32 * 128];   // 16 KB
    __shared__ unsigned short Vs[2][144 * 32];   // 18 KB (rows 128..143: ones/zeros)
    __shared__ unsigned short Ps[4][16][40];     // 5 KB (stride 40: 2-way banks)

    {
        int x = tid * 2;                          // ones region: 16 rows x 32 tok
        unsigned short vv = (x < 32) ? (unsigned short)0x3F80 : (unsigned short)0;
        ushort2 o = {vv, vv};
        *(ushort2*)&Vs[0][128 * 32 + x] = o;
        *(ushort2*)&Vs[1][128 * 32 + x] = o;
    }
    asm volatile("s_waitcnt lgkmcnt(0)" ::: "memory");  // ones visible pre-barrier

    short8 qf[4];
    {
        const unsigned short* qp = Qb + (size_t)(q0 + w * 16 + col) * Q_SIZE + h * HEAD_DIM;
        #pragma unroll
        for (int c = 0; c < 4; ++c)
            qf[c] = *(const short8*)(qp + c * 32 + quad * 8);
    }

    // Staging ptrs: K tile 32x128 = 512 chunks; V tile 128x32 = 512 chunks.
    const unsigned short* kg[2];
    const unsigned short* vg[2];
    #pragma unroll
    for (int it = 0; it < 2; ++it) {
        int s = it * 256 + tid;
        int kr = s >> 4, kp = s & 15, kj = kp ^ (kr & 15);
        kg[it] = Kb + (size_t)kv * T_SEQ * HEAD_DIM + kr * HEAD_DIM + kj * 8;
        int vr = s >> 2, vp = s & 3, vj = vp ^ ((vr >> 1) & 3);
        vg[it] = Vt + (size_t)kv * HEAD_DIM * T_SEQ + (size_t)vr * T_SEQ + vj * 8;
    }

    floatx4 Ob[9];
    #pragma unroll
    for (int cb = 0; cb < 9; ++cb) Ob[cb] = (floatx4){0.f, 0.f, 0.f, 0.f};

    const int wave_qmin = q0 + w * 16;
    const int wave_qmax = wave_qmin + 15;
    const int tok_base = ch * 512;

    #pragma unroll
    for (int it = 0; it < 2; ++it) {
        stage16(kg[it] + (size_t)tok_base * HEAD_DIM, &Ks[0][(it * 256 + w * 64) * 8]);
        stage16(vg[it] + tok_base, &Vs[0][(it * 256 + w * 64) * 8]);
    }

    for (int u = 0; u < units; ++u) {
        const int t0 = tok_base + u * BK;
        if (u + 1 < units) {
            const int tn = t0 + BK;
            const int b = (u + 1) & 1;
            #pragma unroll
            for (int it = 0; it < 2; ++it) {
                stage16(kg[it] + (size_t)tn * HEAD_DIM, &Ks[b][(it * 256 + w * 64) * 8]);
                stage16(vg[it] + tn, &Vs[b][(it * 256 + w * 64) * 8]);
            }
            asm volatile("s_waitcnt vmcnt(4)" ::: "memory");   // tile u ready
        } else {
            asm volatile("s_waitcnt vmcnt(0)" ::: "memory");
        }
        __builtin_amdgcn_s_barrier();          // raw: prefetch stays in flight
        __builtin_amdgcn_sched_barrier(0);

        if (t0 <= wave_qmax) {
            const unsigned short* ks = Ks[u & 1];
            const unsigned short* vs = Vs[u & 1];

            floatx4 S[2];
            #pragma unroll
            for (int cb = 0; cb < 2; ++cb) {
                floatx4 a = (floatx4){0.f, 0.f, 0.f, 0.f};
                #pragma unroll
                for (int c = 0; c < 4; ++c) {
                    short8 kf = *(const short8*)&ks[((cb * 16 + col) * 16 + ((c * 4 + quad) ^ col)) * 8];
                    a = __builtin_amdgcn_mfma_f32_16x16x32_bf16(kf, qf[c], a, 0, 0, 0);
                }
                S[cb] = a;
            }

            const int qr = q0 + w * 16 + col;
            if (t0 + 31 <= wave_qmin) {
                #pragma unroll
                for (int cb = 0; cb < 2; ++cb) {
                    ushort4 pk;
                    pk.x = f2bf(__expf(S[cb][0])); pk.y = f2bf(__expf(S[cb][1]));
                    pk.z = f2bf(__expf(S[cb][2])); pk.w = f2bf(__expf(S[cb][3]));
                    *(ushort4*)&Ps[w][col][cb * 16 + quad * 4] = pk;
                }
            } else {
                #pragma unroll
                for (int cb = 0; cb < 2; ++cb) {
                    int kt = t0 + cb * 16 + quad * 4;
                    ushort4 pk;
                    pk.x = (kt + 0 <= qr) ? f2bf(__expf(S[cb][0])) : (unsigned short)0;
                    pk.y = (kt + 1 <= qr) ? f2bf(__expf(S[cb][1])) : (unsigned short)0;
                    pk.z = (kt + 2 <= qr) ? f2bf(__expf(S[cb][2])) : (unsigned short)0;
                    pk.w = (kt + 3 <= qr) ? f2bf(__expf(S[cb][3])) : (unsigned short)0;
                    *(ushort4*)&Ps[w][col][cb * 16 + quad * 4] = pk;
                }
            }

            short8 pf = *(const short8*)&Ps[w][col][quad * 8];
            #pragma unroll
            for (int cb = 0; cb < 9; ++cb) {
                int vrow = cb * 16 + col;
                short8 vf = *(const short8*)&vs[(vrow * 4 + (quad ^ ((vrow >> 1) & 3))) * 8];
                Ob[cb] = __builtin_amdgcn_mfma_f32_16x16x32_bf16(pf, vf, Ob[cb], 0, 0, 0);
            }
        }
        __builtin_amdgcn_sched_barrier(0);
        asm volatile("" ::: "memory");
        __builtin_amdgcn_s_barrier();          // reads of buf u&1 done before overwrite
    }

    if (qt < 8) {
        // single-chunk: normalize and write ctxb directly
        #pragma unroll
        for (int r = 0; r < 4; ++r) {
            float l = __shfl(Ob[8][r], lane & 48);
            float rl = 1.0f / l;
            const int qrow = q0 + w * 16 + quad * 4 + r;
            #pragma unroll
            for (int cb = 0; cb < 8; ++cb)
                ctxb[(size_t)qrow * Q_SIZE + h * HEAD_DIM + cb * 16 + col] = f2bf(Ob[cb][r] * rl);
        }
    } else {
        const int slot = h * 72 + slot_base(qt) + ch;
        float* po = (slot < 768) ? pO1 + (size_t)slot * (BQ * HEAD_DIM)
                                 : pO2 + (size_t)(slot - 768) * (BQ * HEAD_DIM);
        #pragma unroll
        for (int cb = 0; cb < 8; ++cb)
            #pragma unroll
            for (int r = 0; r < 4; ++r)
                po[(w * 16 + quad * 4 + r) * HEAD_DIM + cb * 16 + col] = Ob[cb][r];
        if (col == 0) {
            #pragma unroll
            for (int r = 0; r < 4; ++r)
                pL[slot * BQ + w * 16 + quad * 4 + r] = Ob[8][r];
        }
    }
}

// ---------------------------------------------------------------------------
// Combine: for qt 8..31, ctx = (sum of nch partial O) / (sum of nch l).
// Grid 384 = 16 heads x 24 qts.
// ---------------------------------------------------------------------------
__global__ __launch_bounds__(256) void combine(
    const float* __restrict__ pO1, const float* __restrict__ pO2,
    const float* __restrict__ pL, unsigned short* __restrict__ ctxb)
{
    const int bx = blockIdx.x;
    const int h = bx / 24;
    const int qt = 8 + (bx % 24);
    const int nch = (qt < 16) ? 2 : (qt < 24) ? 3 : 4;
    const int slot0 = h * 72 + slot_base(qt);
    const int tid = threadIdx.x;
    const int row = tid >> 2;
    const int seg = tid & 3;

    float acc[32];
    #pragma unroll
    for (int m = 0; m < 32; ++m) acc[m] = 0.f;
    float l = 0.f;

    for (int c = 0; c < nch; ++c) {
        const int slot = slot0 + c;
        const float* po = (slot < 768) ? pO1 + (size_t)slot * (BQ * HEAD_DIM)
                                       : pO2 + (size_t)(slot - 768) * (BQ * HEAD_DIM);
        l += pL[slot * BQ + row];
        const float* p = po + row * HEAD_DIM + seg * 32;
        #pragma unroll
        for (int m = 0; m < 8; ++m) {
            float4 a = *(const float4*)(p + m * 4);
            acc[m * 4 + 0] += a.x; acc[m * 4 + 1] += a.y;
            acc[m * 4 + 2] += a.z; acc[m * 4 + 3] += a.w;
        }
    }
    const float rl = 1.0f / l;
    unsigned short* dst = ctxb + (size_t)(qt * BQ + row) * Q_SIZE + h * HEAD_DIM + seg * 32;
    #pragma unroll
    for (int m = 0; m < 8; ++m) {
        ushort4 o;
        o.x = f2bf(acc[m * 4 + 0] * rl); o.y = f2bf(acc[m * 4 + 1] * rl);
        o.z = f2bf(acc[m * 4 + 2] * rl); o.w = f2bf(acc[m * 4 + 3] * rl);
        *(ushort4*)(dst + m * 4) = o;
    }
}

// ---------------------------------------------------------------------------
extern "C" void kernel_launch(void* const* d_in, const int* in_sizes, int n_in,
                              void* d_out, int out_size, void* d_ws, size_t ws_size,
                              hipStream_t stream)
{
    const int*   positions = (const int*)d_in[0];
    const float* hidden    = (const float*)d_in[1];
    const float* qkv_w     = (const float*)d_in[2];
    const float* q_norm_w  = (const float*)d_in[3];
    const float* k_norm_w  = (const float*)d_in[4];
    const float* o_w       = (const float*)d_in[5];
    float* out = (float*)d_out;

    const size_t MB = 1024 * 1024;
    char* ws = (char*)d_ws;
    unsigned short* obf  = (unsigned short*)ws;                 // [0,8)   whole run
    unsigned short* hbf  = (unsigned short*)(ws + 8 * MB);      // [8,16)  dead after QKV GEMM
    unsigned short* wbf  = (unsigned short*)(ws + 16 * MB);     // [16,32) dead after QKV GEMM
    unsigned short* Vt   = (unsigned short*)(ws + 32 * MB);     // [32,36)
    unsigned short* Qb   = (unsigned short*)(ws + 36 * MB);     // [36,44)
    unsigned short* Kb   = (unsigned short*)(ws + 44 * MB);     // [44,48)
    unsigned short* ctxb = (unsigned short*)(ws + 48 * MB);     // [48,56)
    // Attention partials (fp32): slots 0..767 over dead hbf/wbf, slots
    // 768..1151 + partL in d_out (scratch until O-proj overwrites it; combine
    // consumes them first).
    float* pO1 = (float*)(ws + 8 * MB);                         // 24 MB
    float* pO2 = out;                                           // 12 MB
    float* pL  = out + 384 * (BQ * HEAD_DIM);                   // 294 KB

    convert_all<<<(H4 + W4 + O4 + 255) / 256, 256, 0, stream>>>(
        hidden, qkv_w, o_w, hbf, wbf, obf);
    gemm_nt_bf16<1><<<dim3(QKV_N / 128, T_SEQ / 128), 1024, 0, stream>>>(
        hbf, wbf, nullptr, Qb, Kb, Vt, positions, q_norm_w, k_norm_w,
        T_SEQ, QKV_N, HIDDEN_);
    attn_mfma<<<1280, 256, 0, stream>>>(Qb, Kb, Vt, ctxb, pO1, pO2, pL);
    combine<<<384, 256, 0, stream>>>(pO1, pO2, pL, ctxb);
    gemm_o<<<dim3(Q_SIZE / 64, T_SEQ / 64), 512, 0, stream>>>(
        ctxb, obf, out, T_SEQ, Q_SIZE, HIDDEN_);
}

// Round 10
// 216.862 us; speedup vs baseline: 1.0815x; 1.0815x over previous
//
#include <hip/hip_runtime.h>
#include <math.h>

#define T_SEQ     2048
#define HIDDEN_   2048
#define NUM_HEADS 16
#define NUM_KV    8
#define HEAD_DIM  128
#define Q_SIZE    2048
#define KV_SIZE   1024
#define QKV_N     4096
#define QK_N      3072
#define EPS_      1e-6f

typedef __attribute__((ext_vector_type(8))) short short8;
typedef __attribute__((ext_vector_type(4))) float floatx4;

__device__ __forceinline__ unsigned short f2bf(float f) {
    unsigned int u = __float_as_uint(f);
    u += 0x7fffu + ((u >> 16) & 1u);     // RNE
    return (unsigned short)(u >> 16);
}
__device__ __forceinline__ float b2f(unsigned short u) {
    return __uint_as_float((unsigned int)u << 16);
}

__device__ __forceinline__ void stage16(const unsigned short* g, unsigned short* lds_base) {
    __builtin_amdgcn_global_load_lds(
        (const __attribute__((address_space(1))) unsigned int*)g,
        (__attribute__((address_space(3))) unsigned int*)lds_base, 16, 0, 0);
}

// ---------------------------------------------------------------------------
// Fused fp32 -> bf16 conversion of hidden, qkv_w, o_w in ONE launch.
// ---------------------------------------------------------------------------
#define H4 (T_SEQ * HIDDEN_ / 4)
#define W4 (QKV_N * HIDDEN_ / 4)
#define O4 (Q_SIZE * HIDDEN_ / 4)

__global__ __launch_bounds__(256) void convert_all(
    const float* __restrict__ hidden, const float* __restrict__ qkv_w,
    const float* __restrict__ o_w, unsigned short* __restrict__ hbf,
    unsigned short* __restrict__ wbf, unsigned short* __restrict__ obf)
{
    int i = blockIdx.x * 256 + threadIdx.x;
    const float4* src;
    ushort4* dst;
    int j;
    if (i < H4)            { src = (const float4*)hidden; dst = (ushort4*)hbf; j = i; }
    else if (i < H4 + W4)  { src = (const float4*)qkv_w;  dst = (ushort4*)wbf; j = i - H4; }
    else                   { src = (const float4*)o_w;    dst = (ushort4*)obf; j = i - H4 - W4;
                             if (j >= O4) return; }
    float4 v = src[j];
    ushort4 o;
    o.x = f2bf(v.x); o.y = f2bf(v.y); o.z = f2bf(v.z); o.w = f2bf(v.w);
    dst[j] = o;
}

// ---------------------------------------------------------------------------
// bf16 MFMA GEMM (NT), 128x128 tile, 1024 threads / 16 waves, wave-tile 32x32.
// Counted-vmcnt pipeline (BK=64, dbuf, raw s_barrier, never vmcnt(0)
// mid-loop) — unchanged from R14. R18 reverts the O-projection back to this
// kernel (MODE 0): the dedicated 64x64 gemm_o doubled L2 panel traffic and
// regressed (R17 post-mortem).
// MODE 0: C fp32 row-major (O-projection).
// MODE 1 (QKV): q/k: fused RMSNorm + RoPE epilogue; v: transposed Vt store.
// ---------------------------------------------------------------------------
template<int MODE>
__global__ __launch_bounds__(1024, 8) void gemm_nt_bf16(
    const unsigned short* __restrict__ A, const unsigned short* __restrict__ B,
    float* __restrict__ C,
    unsigned short* __restrict__ Qb, unsigned short* __restrict__ Kb,
    unsigned short* __restrict__ Vt,
    const int* __restrict__ positions,
    const float* __restrict__ qw, const float* __restrict__ kw,
    int M, int N, int K)
{
    // smem: As[2][128*64] at 0, Bs[2][128*64] at 16384 (elem offsets). 64 KB.
    __shared__ unsigned short smem[32768];
    unsigned short* const As0 = smem;
    unsigned short* const Bs0 = smem + 16384;

    const int tid  = threadIdx.x;
    const int w    = tid >> 6;           // 0..15
    const int lane = tid & 63;
    const int colL = lane & 15;
    const int quad = lane >> 4;
    const int bm = blockIdx.y * 128;
    const int bn = blockIdx.x * 128;
    const int wr = w >> 2;               // 4 row-groups
    const int wc = w & 3;                // 4 col-groups
    const int wm = wr * 32;
    const int wn = wc * 32;

    floatx4 acc[2][2];
    #pragma unroll
    for (int i = 0; i < 2; ++i)
        #pragma unroll
        for (int j = 0; j < 2; ++j)
            acc[i][j] = (floatx4){0.f, 0.f, 0.f, 0.f};

    // 1024 16B-chunks per matrix per tile; 1024 threads -> 1 chunk each.
    const int s_r  = tid >> 3;
    const int s_lc = (tid & 7) ^ (s_r & 7);

    auto stage_tile = [&](int buf, int k0) {
        stage16(A + (size_t)(bm + s_r) * K + k0 + s_lc * 8,
                As0 + buf * 8192 + tid * 8);
        stage16(B + (size_t)(bn + s_r) * K + k0 + s_lc * 8,
                Bs0 + buf * 8192 + tid * 8);
    };

    const int nt = K >> 6;          // K/64 tiles
    stage_tile(0, 0);               // prologue: 2 loads/thread in flight

    for (int t = 0; t < nt; ++t) {
        const int b = t & 1;
        if (t + 1 < nt) {
            stage_tile(b ^ 1, (t + 1) << 6);              // 2 more in flight
            asm volatile("s_waitcnt vmcnt(2)" ::: "memory"); // tile t ready
        } else {
            asm volatile("s_waitcnt vmcnt(0)" ::: "memory");
        }
        __builtin_amdgcn_s_barrier();        // raw: no vmcnt drain
        __builtin_amdgcn_sched_barrier(0);

        const unsigned short* la = As0 + b * 8192;
        const unsigned short* lb = Bs0 + b * 8192;
        #pragma unroll
        for (int kk = 0; kk < 2; ++kk) {
            short8 af[2], bfv[2];
            #pragma unroll
            for (int i = 0; i < 2; ++i) {
                int ra = wm + i * 16 + colL;
                af[i]  = *(const short8*)&la[ra * 64 + (((kk * 4 + quad) ^ (ra & 7)) * 8)];
            }
            #pragma unroll
            for (int j = 0; j < 2; ++j) {
                int rb = wn + j * 16 + colL;
                bfv[j] = *(const short8*)&lb[rb * 64 + (((kk * 4 + quad) ^ (rb & 7)) * 8)];
            }
            #pragma unroll
            for (int i = 0; i < 2; ++i)
                #pragma unroll
                for (int j = 0; j < 2; ++j)
                    acc[i][j] = __builtin_amdgcn_mfma_f32_16x16x32_bf16(af[i], bfv[j], acc[i][j], 0, 0, 0);
        }
        __builtin_amdgcn_sched_barrier(0);
        asm volatile("" ::: "memory");
        __builtin_amdgcn_s_barrier();        // all reads of buf b done before overwrite
    }

    if constexpr (MODE == 0) {
        #pragma unroll
        for (int i = 0; i < 2; ++i)
            #pragma unroll
            for (int j = 0; j < 2; ++j)
                #pragma unroll
                for (int rr = 0; rr < 4; ++rr) {
                    int row = bm + wm + i * 16 + quad * 4 + rr;
                    int cc2 = bn + wn + j * 16 + colL;
                    C[(size_t)row * N + cc2] = acc[i][j][rr];
                }
    } else {
        if (bn < QK_N) {
            // ---------- Phase A: RMSNorm, acc -> bf16 xnL, acc dies ----------
            __shared__ float sums[4][128];
            unsigned short* xnL = smem;     // overlay: [d][row], stride 132

            float p[2][4];
            #pragma unroll
            for (int i = 0; i < 2; ++i)
                #pragma unroll
                for (int rr = 0; rr < 4; ++rr) {
                    float sv = 0.f;
                    #pragma unroll
                    for (int j = 0; j < 2; ++j)
                        sv = fmaf(acc[i][j][rr], acc[i][j][rr], sv);
                    p[i][rr] = sv;
                }
            #pragma unroll
            for (int off = 1; off < 16; off <<= 1)
                #pragma unroll
                for (int i = 0; i < 2; ++i)
                    #pragma unroll
                    for (int rr = 0; rr < 4; ++rr)
                        p[i][rr] += __shfl_xor(p[i][rr], off, 64);
            if (colL == 0) {
                #pragma unroll
                for (int i = 0; i < 2; ++i)
                    #pragma unroll
                    for (int rr = 0; rr < 4; ++rr)
                        sums[wc][wm + i * 16 + quad * 4 + rr] = p[i][rr];
            }
            __syncthreads();

            float inv_r[2][4];
            #pragma unroll
            for (int i = 0; i < 2; ++i)
                #pragma unroll
                for (int rr = 0; rr < 4; ++rr) {
                    int row = wm + i * 16 + quad * 4 + rr;
                    float tot = (sums[0][row] + sums[1][row]) + (sums[2][row] + sums[3][row]);
                    inv_r[i][rr] = rsqrtf(tot * (1.0f / HEAD_DIM) + EPS_);
                }

            const float* nw = (bn < Q_SIZE) ? qw : kw;
            float wv[2];
            #pragma unroll
            for (int j = 0; j < 2; ++j)
                wv[j] = nw[wn + j * 16 + colL];

            #pragma unroll
            for (int i = 0; i < 2; ++i)
                #pragma unroll
                for (int j = 0; j < 2; ++j) {
                    ushort4 pk;
                    pk.x = f2bf(acc[i][j][0] * inv_r[i][0] * wv[j]);
                    pk.y = f2bf(acc[i][j][1] * inv_r[i][1] * wv[j]);
                    pk.z = f2bf(acc[i][j][2] * inv_r[i][2] * wv[j]);
                    pk.w = f2bf(acc[i][j][3] * inv_r[i][3] * wv[j]);
                    int d = wn + j * 16 + colL;
                    *(ushort4*)&xnL[d * 132 + wm + i * 16 + quad * 4] = pk;
                }
            __syncthreads();
            // ---------- Phase B: RoPE from LDS only (no acc liveness) ----------
            // 1024 threads: thread -> (row r = tid>>3, freq octant oct = tid&7);
            // 8 sincos/thread, each produces BOTH d and d+64; ushort4 stores.
            {
                const int r = tid >> 3;
                const int oct = tid & 7;
                const float pos = (float)positions[bm + r];
                const bool is_q = (bn < Q_SIZE);
                const float l2r = 13.287712379549449f / 64.0f;
                const float sc = 0.08838834764831845f;
                unsigned short* rowp;
                if (is_q) rowp = Qb + (size_t)(bm + r) * Q_SIZE + (bn >> 7) * HEAD_DIM;
                else      rowp = Kb + ((size_t)((bn - Q_SIZE) >> 7) * T_SEQ + bm + r) * HEAD_DIM;

                #pragma unroll
                for (int f4 = 0; f4 < 8; f4 += 4) {
                    ushort4 lo, hi;
                    #pragma unroll
                    for (int e = 0; e < 4; ++e) {
                        int f = oct * 8 + f4 + e;
                        float x1 = b2f(xnL[f * 132 + r]);          // d = f
                        float x2 = b2f(xnL[(f + 64) * 132 + r]);   // d = f+64
                        float sv, cv;
                        __sincosf(pos * exp2f(-(float)f * l2r), &sv, &cv);
                        float olo = fmaf(x1, cv, -x2 * sv);
                        float ohi = fmaf(x2, cv,  x1 * sv);
                        if (is_q) { olo *= sc; ohi *= sc; }
                        ((unsigned short*)&lo)[e] = f2bf(olo);
                        ((unsigned short*)&hi)[e] = f2bf(ohi);
                    }
                    *(ushort4*)(rowp + oct * 8 + f4)      = lo;
                    *(ushort4*)(rowp + 64 + oct * 8 + f4) = hi;
                }
            }
        } else {
            const int kvh = (bn - QK_N) >> 7;
            #pragma unroll
            for (int i = 0; i < 2; ++i)
                #pragma unroll
                for (int j = 0; j < 2; ++j) {
                    int d = wn + j * 16 + colL;
                    int tok = bm + wm + i * 16 + quad * 4;
                    ushort4 o;
                    o.x = f2bf(acc[i][j][0]); o.y = f2bf(acc[i][j][1]);
                    o.z = f2bf(acc[i][j][2]); o.w = f2bf(acc[i][j][3]);
                    *(ushort4*)&Vt[((size_t)kvh * HEAD_DIM + d) * T_SEQ + tok] = o;
                }
        }
    }
}

// ---------------------------------------------------------------------------
// Flash attention, R18: R15 structure (BK=32, 1024-token chunks, counted
// vmcnt + raw barriers) with ALL LDS read addresses hoisted out of the unit
// loop. VALUBusy was 39% vs MfmaUtil 14.5% — per-unit swizzle/address math
// on ~27 ds_reads dominated VALU. The swizzled offsets decompose into
// per-thread constants + compile-time immediates:
//   kf byte off = cb*4096 + [col*256 + ((c*4+quad)^col)*16]
//   vf byte off = cb*1024 + [col*64  + (quad^((col>>1)&3))*16]
// (brackets loop-invariant; cb folds into ds_read offset: immediates).
// The unit loop is unrolled by 2 (units is always even) so the double-buffer
// pointer sets are statically indexed (rule #20: no runtime-indexed arrays).
// ---------------------------------------------------------------------------
#define BQ 64
#define BK 32

__global__ __launch_bounds__(256) void attn_mfma(
    const unsigned short* __restrict__ Qb, const unsigned short* __restrict__ Kb,
    const unsigned short* __restrict__ Vt, unsigned short* __restrict__ ctxb,
    float* __restrict__ partO, float* __restrict__ partL)
{
    const int h = blockIdx.y;
    int qt, ch;
    {
        int x = blockIdx.x;
        if (x < 16) { qt = 16 + x; ch = 0; }
        else {
            int p = (x - 16) >> 1;
            if (((x - 16) & 1) == 0) { qt = 15 - p; ch = 0; }
            else                     { qt = 31 - p; ch = 1; }
        }
    }
    const int nch = (qt >= 16) ? 2 : 1;
    // units are BK=32 steps; a 1024-token chunk is 32 units. Always EVEN.
    const int units = (ch == 0) ? ((qt + 1 < 16) ? 2 * (qt + 1) : 32)
                                : (2 * (qt + 1) - 32);
    const int q0 = qt * BQ;
    const int kv = h >> 1;
    const int tid = threadIdx.x;
    const int w = tid >> 6;
    const int lane = tid & 63;
    const int col = lane & 15;
    const int quad = lane >> 4;

    __shared__ unsigned short Ks[2][32 * 128];   // 16 KB
    __shared__ unsigned short Vs[2][144 * 32];   // 18 KB (rows 128..143: ones/zeros)
    __shared__ unsigned short Ps[4][16][40];     // 5 KB (stride 40: 2-way banks)

    {
        int x = tid * 2;                          // ones region: 16 rows x 32 tok
        unsigned short vv = (x < 32) ? (unsigned short)0x3F80 : (unsigned short)0;
        ushort2 o = {vv, vv};
        *(ushort2*)&Vs[0][128 * 32 + x] = o;
        *(ushort2*)&Vs[1][128 * 32 + x] = o;
    }
    asm volatile("s_waitcnt lgkmcnt(0)" ::: "memory");  // ones visible pre-barrier

    short8 qf[4];
    {
        const unsigned short* qp = Qb + (size_t)(q0 + w * 16 + col) * Q_SIZE + h * HEAD_DIM;
        #pragma unroll
        for (int c = 0; c < 4; ++c)
            qf[c] = *(const short8*)(qp + c * 32 + quad * 8);
    }

    // Staging ptrs: K tile 32x128 = 512 chunks; V tile 128x32 = 512 chunks.
    const unsigned short* kg[2];
    const unsigned short* vg[2];
    #pragma unroll
    for (int it = 0; it < 2; ++it) {
        int s = it * 256 + tid;
        int kr = s >> 4, kp = s & 15, kj = kp ^ (kr & 15);
        kg[it] = Kb + (size_t)kv * T_SEQ * HEAD_DIM + kr * HEAD_DIM + kj * 8;
        int vr = s >> 2, vp = s & 3, vj = vp ^ ((vr >> 1) & 3);
        vg[it] = Vt + (size_t)kv * HEAD_DIM * T_SEQ + (size_t)vr * T_SEQ + vj * 8;
    }

    // ---- Hoisted per-thread LDS read bases (loop-invariant) ----
    const int kconst = col * 256;                         // bytes
    const char* k00 = (const char*)Ks[0] + kconst + (((0 * 4 + quad) ^ col) * 16);
    const char* k01 = (const char*)Ks[0] + kconst + (((1 * 4 + quad) ^ col) * 16);
    const char* k02 = (const char*)Ks[0] + kconst + (((2 * 4 + quad) ^ col) * 16);
    const char* k03 = (const char*)Ks[0] + kconst + (((3 * 4 + quad) ^ col) * 16);
    const char* k10 = (const char*)Ks[1] + kconst + (((0 * 4 + quad) ^ col) * 16);
    const char* k11 = (const char*)Ks[1] + kconst + (((1 * 4 + quad) ^ col) * 16);
    const char* k12 = (const char*)Ks[1] + kconst + (((2 * 4 + quad) ^ col) * 16);
    const char* k13 = (const char*)Ks[1] + kconst + (((3 * 4 + quad) ^ col) * 16);
    const int vconst = col * 64 + ((quad ^ ((col >> 1) & 3)) * 16);   // bytes
    const char* v0 = (const char*)Vs[0] + vconst;
    const char* v1 = (const char*)Vs[1] + vconst;
    char* psw = (char*)&Ps[w][col][quad * 4];             // write base (+cb*32 B)
    const char* psr = (const char*)&Ps[w][col][quad * 8]; // read base

    floatx4 Ob[9];
    #pragma unroll
    for (int cb = 0; cb < 9; ++cb) Ob[cb] = (floatx4){0.f, 0.f, 0.f, 0.f};

    const int wave_qmin = q0 + w * 16;
    const int wave_qmax = wave_qmin + 15;
    const int tok_base = ch * 1024;

    #pragma unroll
    for (int it = 0; it < 2; ++it) {
        stage16(kg[it] + (size_t)tok_base * HEAD_DIM, &Ks[0][(it * 256 + w * 64) * 8]);
        stage16(vg[it] + tok_base, &Vs[0][(it * 256 + w * 64) * 8]);
    }

    auto body = [&](int u, const char* kb0, const char* kb1, const char* kb2,
                    const char* kb3, const char* vb,
                    unsigned short* KsN, unsigned short* VsN) {
        const int t0 = tok_base + u * BK;
        if (u + 1 < units) {
            const int tn = t0 + BK;
            #pragma unroll
            for (int it = 0; it < 2; ++it) {
                stage16(kg[it] + (size_t)tn * HEAD_DIM, &KsN[(it * 256 + w * 64) * 8]);
                stage16(vg[it] + tn, &VsN[(it * 256 + w * 64) * 8]);
            }
            asm volatile("s_waitcnt vmcnt(4)" ::: "memory");   // tile u ready
        } else {
            asm volatile("s_waitcnt vmcnt(0)" ::: "memory");
        }
        __builtin_amdgcn_s_barrier();          // raw: prefetch stays in flight
        __builtin_amdgcn_sched_barrier(0);

        if (t0 <= wave_qmax) {
            floatx4 S[2];
            #pragma unroll
            for (int cb = 0; cb < 2; ++cb) {
                floatx4 a = (floatx4){0.f, 0.f, 0.f, 0.f};
                a = __builtin_amdgcn_mfma_f32_16x16x32_bf16(*(const short8*)(kb0 + cb * 4096), qf[0], a, 0, 0, 0);
                a = __builtin_amdgcn_mfma_f32_16x16x32_bf16(*(const short8*)(kb1 + cb * 4096), qf[1], a, 0, 0, 0);
                a = __builtin_amdgcn_mfma_f32_16x16x32_bf16(*(const short8*)(kb2 + cb * 4096), qf[2], a, 0, 0, 0);
                a = __builtin_amdgcn_mfma_f32_16x16x32_bf16(*(const short8*)(kb3 + cb * 4096), qf[3], a, 0, 0, 0);
                S[cb] = a;
            }

            const int qr = q0 + w * 16 + col;
            if (t0 + 31 <= wave_qmin) {
                #pragma unroll
                for (int cb = 0; cb < 2; ++cb) {
                    ushort4 pk;
                    pk.x = f2bf(__expf(S[cb][0])); pk.y = f2bf(__expf(S[cb][1]));
                    pk.z = f2bf(__expf(S[cb][2])); pk.w = f2bf(__expf(S[cb][3]));
                    *(ushort4*)(psw + cb * 32) = pk;
                }
            } else {
                #pragma unroll
                for (int cb = 0; cb < 2; ++cb) {
                    int kt = t0 + cb * 16 + quad * 4;
                    ushort4 pk;
                    pk.x = (kt + 0 <= qr) ? f2bf(__expf(S[cb][0])) : (unsigned short)0;
                    pk.y = (kt + 1 <= qr) ? f2bf(__expf(S[cb][1])) : (unsigned short)0;
                    pk.z = (kt + 2 <= qr) ? f2bf(__expf(S[cb][2])) : (unsigned short)0;
                    pk.w = (kt + 3 <= qr) ? f2bf(__expf(S[cb][3])) : (unsigned short)0;
                    *(ushort4*)(psw + cb * 32) = pk;
                }
            }

            short8 pf = *(const short8*)psr;
            #pragma unroll
            for (int cb = 0; cb < 9; ++cb)
                Ob[cb] = __builtin_amdgcn_mfma_f32_16x16x32_bf16(
                    pf, *(const short8*)(vb + cb * 1024), Ob[cb], 0, 0, 0);
        }
        __builtin_amdgcn_sched_barrier(0);
        asm volatile("" ::: "memory");
        __builtin_amdgcn_s_barrier();          // reads of this buf done before overwrite
    };

    for (int u = 0; u < units; u += 2) {
        body(u,     k00, k01, k02, k03, v0, Ks[1], Vs[1]);   // buf 0, prefetch -> 1
        body(u + 1, k10, k11, k12, k13, v1, Ks[0], Vs[0]);   // buf 1, prefetch -> 0
    }

    if (nch == 1) {
        #pragma unroll
        for (int r = 0; r < 4; ++r) {
            float l = __shfl(Ob[8][r], lane & 48);
            float rl = 1.0f / l;
            const int qrow = q0 + w * 16 + quad * 4 + r;
            #pragma unroll
            for (int cb = 0; cb < 8; ++cb)
                ctxb[(size_t)qrow * Q_SIZE + h * HEAD_DIM + cb * 16 + col] = f2bf(Ob[cb][r] * rl);
        }
    } else {
        const int slot = (h * 16 + (qt - 16)) * 2 + ch;
        float* po = partO + (size_t)slot * (BQ * HEAD_DIM);
        #pragma unroll
        for (int cb = 0; cb < 8; ++cb)
            #pragma unroll
            for (int r = 0; r < 4; ++r)
                po[(w * 16 + quad * 4 + r) * HEAD_DIM + cb * 16 + col] = Ob[cb][r];
        if (col == 0) {
            #pragma unroll
            for (int r = 0; r < 4; ++r)
                partL[slot * BQ + w * 16 + quad * 4 + r] = Ob[8][r];
        }
    }
}

// ---------------------------------------------------------------------------
// Combine: ctx[qt>=16] = (O0 + O1) / (l0 + l1).
// ---------------------------------------------------------------------------
__global__ __launch_bounds__(256) void combine(
    const float* __restrict__ partO, const float* __restrict__ partL,
    unsigned short* __restrict__ ctxb)
{
    const int h = blockIdx.x >> 4;
    const int qi = blockIdx.x & 15;
    const int q0 = (16 + qi) * 64;
    const int slot0 = (h * 16 + qi) * 2;
    const int tid = threadIdx.x;
    const int row = tid >> 2;
    const int seg = tid & 3;

    const float l = partL[slot0 * 64 + row] + partL[(slot0 + 1) * 64 + row];
    const float rl = 1.0f / l;
    const float* p0 = partO + (size_t)slot0 * 8192 + row * 128 + seg * 32;
    const float* p1 = p0 + 8192;
    unsigned short* dst = ctxb + (size_t)(q0 + row) * Q_SIZE + h * HEAD_DIM + seg * 32;
    #pragma unroll
    for (int m = 0; m < 8; ++m) {
        float4 a = *(const float4*)(p0 + m * 4);
        float4 b = *(const float4*)(p1 + m * 4);
        ushort4 o;
        o.x = f2bf((a.x + b.x) * rl); o.y = f2bf((a.y + b.y) * rl);
        o.z = f2bf((a.z + b.z) * rl); o.w = f2bf((a.w + b.w) * rl);
        *(ushort4*)(dst + m * 4) = o;
    }
}

// ---------------------------------------------------------------------------
extern "C" void kernel_launch(void* const* d_in, const int* in_sizes, int n_in,
                              void* d_out, int out_size, void* d_ws, size_t ws_size,
                              hipStream_t stream)
{
    const int*   positions = (const int*)d_in[0];
    const float* hidden    = (const float*)d_in[1];
    const float* qkv_w     = (const float*)d_in[2];
    const float* q_norm_w  = (const float*)d_in[3];
    const float* k_norm_w  = (const float*)d_in[4];
    const float* o_w       = (const float*)d_in[5];
    float* out = (float*)d_out;

    const size_t MB = 1024 * 1024;
    char* ws = (char*)d_ws;
    unsigned short* obf  = (unsigned short*)ws;                 // [0,8)   whole run
    unsigned short* hbf  = (unsigned short*)(ws + 8 * MB);      // [8,16)  dead after QKV GEMM
    unsigned short* wbf  = (unsigned short*)(ws + 16 * MB);     // [16,32) dead after QKV GEMM
    unsigned short* Vt   = (unsigned short*)(ws + 32 * MB);     // [32,36)
    unsigned short* Qb   = (unsigned short*)(ws + 36 * MB);     // [36,44)
    unsigned short* Kb   = (unsigned short*)(ws + 44 * MB);     // [44,48)
    unsigned short* ctxb = (unsigned short*)(ws + 48 * MB);     // [48,56)
    float* partL         = (float*)(ws + 8 * MB);               // [8,8.125) over dead hbf
    float* partO         = (float*)(ws + 16 * MB);              // [16,32) over dead wbf (16 MB)

    convert_all<<<(H4 + W4 + O4 + 255) / 256, 256, 0, stream>>>(
        hidden, qkv_w, o_w, hbf, wbf, obf);
    gemm_nt_bf16<1><<<dim3(QKV_N / 128, T_SEQ / 128), 1024, 0, stream>>>(
        hbf, wbf, nullptr, Qb, Kb, Vt, positions, q_norm_w, k_norm_w,
        T_SEQ, QKV_N, HIDDEN_);
    attn_mfma<<<dim3(48, NUM_HEADS), 256, 0, stream>>>(Qb, Kb, Vt, ctxb, partO, partL);
    combine<<<256, 256, 0, stream>>>(partO, partL, ctxb);
    gemm_nt_bf16<0><<<dim3(Q_SIZE / 128, T_SEQ / 128), 1024, 0, stream>>>(
        ctxb, obf, out, nullptr, nullptr, nullptr, nullptr, nullptr, nullptr,
        T_SEQ, Q_SIZE, HIDDEN_);
}

// Round 11
// 216.481 us; speedup vs baseline: 1.0834x; 1.0018x over previous
//
#include <hip/hip_runtime.h>
#include <math.h>

#define T_SEQ     2048
#define HIDDEN_   2048
#define NUM_HEADS 16
#define NUM_KV    8
#define HEAD_DIM  128
#define Q_SIZE    2048
#define KV_SIZE   1024
#define QKV_N     4096
#define QK_N      3072
#define EPS_      1e-6f

typedef __attribute__((ext_vector_type(8))) short short8;
typedef __attribute__((ext_vector_type(4))) float floatx4;

__device__ __forceinline__ unsigned short f2bf(float f) {
    unsigned int u = __float_as_uint(f);
    u += 0x7fffu + ((u >> 16) & 1u);     // RNE
    return (unsigned short)(u >> 16);
}
__device__ __forceinline__ float b2f(unsigned short u) {
    return __uint_as_float((unsigned int)u << 16);
}

__device__ __forceinline__ void stage16(const unsigned short* g, unsigned short* lds_base) {
    __builtin_amdgcn_global_load_lds(
        (const __attribute__((address_space(1))) unsigned int*)g,
        (__attribute__((address_space(3))) unsigned int*)lds_base, 16, 0, 0);
}

// ---------------------------------------------------------------------------
// Fused fp32 -> bf16 conversion of hidden, qkv_w, o_w in ONE launch.
// ---------------------------------------------------------------------------
#define H4 (T_SEQ * HIDDEN_ / 4)
#define W4 (QKV_N * HIDDEN_ / 4)
#define O4 (Q_SIZE * HIDDEN_ / 4)

__global__ __launch_bounds__(256) void convert_all(
    const float* __restrict__ hidden, const float* __restrict__ qkv_w,
    const float* __restrict__ o_w, unsigned short* __restrict__ hbf,
    unsigned short* __restrict__ wbf, unsigned short* __restrict__ obf)
{
    int i = blockIdx.x * 256 + threadIdx.x;
    const float4* src;
    ushort4* dst;
    int j;
    if (i < H4)            { src = (const float4*)hidden; dst = (ushort4*)hbf; j = i; }
    else if (i < H4 + W4)  { src = (const float4*)qkv_w;  dst = (ushort4*)wbf; j = i - H4; }
    else                   { src = (const float4*)o_w;    dst = (ushort4*)obf; j = i - H4 - W4;
                             if (j >= O4) return; }
    float4 v = src[j];
    ushort4 o;
    o.x = f2bf(v.x); o.y = f2bf(v.y); o.z = f2bf(v.z); o.w = f2bf(v.w);
    dst[j] = o;
}

// ---------------------------------------------------------------------------
// bf16 MFMA GEMM (NT), 128x128 tile, 1024 threads / 16 waves, wave-tile 32x32.
// R19: same counted-vmcnt pipeline (BK=64, dbuf, raw s_barrier), but ALL LDS
// read addresses hoisted out of the K-loop — same fix that moved attn out of
// the top-5 in R18. VALUBusy 31% ~= MfmaUtil 30% showed the compiler
// recomputes the swizzle/address chains every K-step; all 16 read pointers
// (2 af + 2 bfv x 2 kk x 2 buffers), the 2 global stage bases, and the 4 LDS
// stage dests are loop-invariant. t-loop unrolled by 2 (nt=32, even) so
// buffer selection is static.
// MODE 0: C fp32 row-major (O-projection).
// MODE 1 (QKV): q/k: fused RMSNorm + RoPE epilogue; v: transposed Vt store.
// ---------------------------------------------------------------------------
template<int MODE>
__global__ __launch_bounds__(1024, 8) void gemm_nt_bf16(
    const unsigned short* __restrict__ A, const unsigned short* __restrict__ B,
    float* __restrict__ C,
    unsigned short* __restrict__ Qb, unsigned short* __restrict__ Kb,
    unsigned short* __restrict__ Vt,
    const int* __restrict__ positions,
    const float* __restrict__ qw, const float* __restrict__ kw,
    int M, int N, int K)
{
    // smem: As[2][128*64] at 0, Bs[2][128*64] at 16384 (elem offsets). 64 KB.
    __shared__ unsigned short smem[32768];
    unsigned short* const As0 = smem;
    unsigned short* const Bs0 = smem + 16384;

    const int tid  = threadIdx.x;
    const int w    = tid >> 6;           // 0..15
    const int lane = tid & 63;
    const int colL = lane & 15;
    const int quad = lane >> 4;
    const int bm = blockIdx.y * 128;
    const int bn = blockIdx.x * 128;
    const int wr = w >> 2;               // 4 row-groups
    const int wc = w & 3;                // 4 col-groups
    const int wm = wr * 32;
    const int wn = wc * 32;

    floatx4 acc[2][2];
    #pragma unroll
    for (int i = 0; i < 2; ++i)
        #pragma unroll
        for (int j = 0; j < 2; ++j)
            acc[i][j] = (floatx4){0.f, 0.f, 0.f, 0.f};

    // 1024 16B-chunks per matrix per tile; 1024 threads -> 1 chunk each.
    const int s_r  = tid >> 3;
    const int s_lc = (tid & 7) ^ (s_r & 7);

    // ---- Hoisted staging bases (loop-invariant) ----
    const unsigned short* gA = A + (size_t)(bm + s_r) * K + s_lc * 8;
    const unsigned short* gB = B + (size_t)(bn + s_r) * K + s_lc * 8;
    unsigned short* dA0 = As0 + tid * 8;
    unsigned short* dA1 = dA0 + 8192;
    unsigned short* dB0 = Bs0 + tid * 8;
    unsigned short* dB1 = dB0 + 8192;

    // ---- Hoisted LDS read pointers (loop-invariant) ----
    // byte off = r*128 + (((kk*4+quad)^(r&7))*16), r thread-constant.
    const int ra0 = wm + colL, ra1 = wm + 16 + colL;
    const int rb0 = wn + colL, rb1 = wn + 16 + colL;
    const char* pA0[2][2]; const char* pA1[2][2];
    const char* pB0[2][2]; const char* pB1[2][2];
    #pragma unroll
    for (int kk = 0; kk < 2; ++kk) {
        int oa0 = ra0 * 128 + (((kk * 4 + quad) ^ (ra0 & 7)) * 16);
        int oa1 = ra1 * 128 + (((kk * 4 + quad) ^ (ra1 & 7)) * 16);
        int ob0 = rb0 * 128 + (((kk * 4 + quad) ^ (rb0 & 7)) * 16);
        int ob1 = rb1 * 128 + (((kk * 4 + quad) ^ (rb1 & 7)) * 16);
        pA0[kk][0] = (const char*)As0 + oa0;  pA0[kk][1] = (const char*)As0 + oa1;
        pA1[kk][0] = pA0[kk][0] + 16384;      pA1[kk][1] = pA0[kk][1] + 16384;
        pB0[kk][0] = (const char*)Bs0 + ob0;  pB0[kk][1] = (const char*)Bs0 + ob1;
        pB1[kk][0] = pB0[kk][0] + 16384;      pB1[kk][1] = pB0[kk][1] + 16384;
    }

    const int nt = K >> 6;          // K/64 tiles (32 — even)

    stage16(gA, dA0);               // prologue: tile 0 -> buf 0
    stage16(gB, dB0);

    auto body = [&](int t, const char* const pA[2][2], const char* const pB[2][2],
                    unsigned short* dAn, unsigned short* dBn) {
        if (t + 1 < nt) {
            const int k0 = (t + 1) << 6;
            stage16(gA + k0, dAn);
            stage16(gB + k0, dBn);
            asm volatile("s_waitcnt vmcnt(2)" ::: "memory"); // tile t ready
        } else {
            asm volatile("s_waitcnt vmcnt(0)" ::: "memory");
        }
        __builtin_amdgcn_s_barrier();        // raw: no vmcnt drain
        __builtin_amdgcn_sched_barrier(0);

        #pragma unroll
        for (int kk = 0; kk < 2; ++kk) {
            short8 af0 = *(const short8*)pA[kk][0];
            short8 af1 = *(const short8*)pA[kk][1];
            short8 bf0 = *(const short8*)pB[kk][0];
            short8 bf1 = *(const short8*)pB[kk][1];
            acc[0][0] = __builtin_amdgcn_mfma_f32_16x16x32_bf16(af0, bf0, acc[0][0], 0, 0, 0);
            acc[0][1] = __builtin_amdgcn_mfma_f32_16x16x32_bf16(af0, bf1, acc[0][1], 0, 0, 0);
            acc[1][0] = __builtin_amdgcn_mfma_f32_16x16x32_bf16(af1, bf0, acc[1][0], 0, 0, 0);
            acc[1][1] = __builtin_amdgcn_mfma_f32_16x16x32_bf16(af1, bf1, acc[1][1], 0, 0, 0);
        }
        __builtin_amdgcn_sched_barrier(0);
        asm volatile("" ::: "memory");
        __builtin_amdgcn_s_barrier();        // reads of this buf done before overwrite
    };

    for (int t = 0; t < nt; t += 2) {
        body(t,     pA0, pB0, dA1, dB1);     // buf 0, prefetch -> buf 1
        body(t + 1, pA1, pB1, dA0, dB0);     // buf 1, prefetch -> buf 0
    }

    if constexpr (MODE == 0) {
        #pragma unroll
        for (int i = 0; i < 2; ++i)
            #pragma unroll
            for (int j = 0; j < 2; ++j)
                #pragma unroll
                for (int rr = 0; rr < 4; ++rr) {
                    int row = bm + wm + i * 16 + quad * 4 + rr;
                    int cc2 = bn + wn + j * 16 + colL;
                    C[(size_t)row * N + cc2] = acc[i][j][rr];
                }
    } else {
        if (bn < QK_N) {
            // ---------- Phase A: RMSNorm, acc -> bf16 xnL, acc dies ----------
            __shared__ float sums[4][128];
            unsigned short* xnL = smem;     // overlay: [d][row], stride 132

            float p[2][4];
            #pragma unroll
            for (int i = 0; i < 2; ++i)
                #pragma unroll
                for (int rr = 0; rr < 4; ++rr) {
                    float sv = 0.f;
                    #pragma unroll
                    for (int j = 0; j < 2; ++j)
                        sv = fmaf(acc[i][j][rr], acc[i][j][rr], sv);
                    p[i][rr] = sv;
                }
            #pragma unroll
            for (int off = 1; off < 16; off <<= 1)
                #pragma unroll
                for (int i = 0; i < 2; ++i)
                    #pragma unroll
                    for (int rr = 0; rr < 4; ++rr)
                        p[i][rr] += __shfl_xor(p[i][rr], off, 64);
            if (colL == 0) {
                #pragma unroll
                for (int i = 0; i < 2; ++i)
                    #pragma unroll
                    for (int rr = 0; rr < 4; ++rr)
                        sums[wc][wm + i * 16 + quad * 4 + rr] = p[i][rr];
            }
            __syncthreads();

            float inv_r[2][4];
            #pragma unroll
            for (int i = 0; i < 2; ++i)
                #pragma unroll
                for (int rr = 0; rr < 4; ++rr) {
                    int row = wm + i * 16 + quad * 4 + rr;
                    float tot = (sums[0][row] + sums[1][row]) + (sums[2][row] + sums[3][row]);
                    inv_r[i][rr] = rsqrtf(tot * (1.0f / HEAD_DIM) + EPS_);
                }

            const float* nw = (bn < Q_SIZE) ? qw : kw;
            float wv[2];
            #pragma unroll
            for (int j = 0; j < 2; ++j)
                wv[j] = nw[wn + j * 16 + colL];

            #pragma unroll
            for (int i = 0; i < 2; ++i)
                #pragma unroll
                for (int j = 0; j < 2; ++j) {
                    ushort4 pk;
                    pk.x = f2bf(acc[i][j][0] * inv_r[i][0] * wv[j]);
                    pk.y = f2bf(acc[i][j][1] * inv_r[i][1] * wv[j]);
                    pk.z = f2bf(acc[i][j][2] * inv_r[i][2] * wv[j]);
                    pk.w = f2bf(acc[i][j][3] * inv_r[i][3] * wv[j]);
                    int d = wn + j * 16 + colL;
                    *(ushort4*)&xnL[d * 132 + wm + i * 16 + quad * 4] = pk;
                }
            __syncthreads();
            // ---------- Phase B: RoPE from LDS only (no acc liveness) ----------
            // 1024 threads: thread -> (row r = tid>>3, freq octant oct = tid&7);
            // 8 sincos/thread, each produces BOTH d and d+64; ushort4 stores.
            {
                const int r = tid >> 3;
                const int oct = tid & 7;
                const float pos = (float)positions[bm + r];
                const bool is_q = (bn < Q_SIZE);
                const float l2r = 13.287712379549449f / 64.0f;
                const float sc = 0.08838834764831845f;
                unsigned short* rowp;
                if (is_q) rowp = Qb + (size_t)(bm + r) * Q_SIZE + (bn >> 7) * HEAD_DIM;
                else      rowp = Kb + ((size_t)((bn - Q_SIZE) >> 7) * T_SEQ + bm + r) * HEAD_DIM;

                #pragma unroll
                for (int f4 = 0; f4 < 8; f4 += 4) {
                    ushort4 lo, hi;
                    #pragma unroll
                    for (int e = 0; e < 4; ++e) {
                        int f = oct * 8 + f4 + e;
                        float x1 = b2f(xnL[f * 132 + r]);          // d = f
                        float x2 = b2f(xnL[(f + 64) * 132 + r]);   // d = f+64
                        float sv, cv;
                        __sincosf(pos * exp2f(-(float)f * l2r), &sv, &cv);
                        float olo = fmaf(x1, cv, -x2 * sv);
                        float ohi = fmaf(x2, cv,  x1 * sv);
                        if (is_q) { olo *= sc; ohi *= sc; }
                        ((unsigned short*)&lo)[e] = f2bf(olo);
                        ((unsigned short*)&hi)[e] = f2bf(ohi);
                    }
                    *(ushort4*)(rowp + oct * 8 + f4)      = lo;
                    *(ushort4*)(rowp + 64 + oct * 8 + f4) = hi;
                }
            }
        } else {
            const int kvh = (bn - QK_N) >> 7;
            #pragma unroll
            for (int i = 0; i < 2; ++i)
                #pragma unroll
                for (int j = 0; j < 2; ++j) {
                    int d = wn + j * 16 + colL;
                    int tok = bm + wm + i * 16 + quad * 4;
                    ushort4 o;
                    o.x = f2bf(acc[i][j][0]); o.y = f2bf(acc[i][j][1]);
                    o.z = f2bf(acc[i][j][2]); o.w = f2bf(acc[i][j][3]);
                    *(ushort4*)&Vt[((size_t)kvh * HEAD_DIM + d) * T_SEQ + tok] = o;
                }
        }
    }
}

// ---------------------------------------------------------------------------
// Flash attention, R18 structure (BK=32, counted vmcnt + raw barriers, all
// LDS read addresses hoisted, unit loop unrolled by 2) — unchanged from R10.
// ---------------------------------------------------------------------------
#define BQ 64
#define BK 32

__global__ __launch_bounds__(256) void attn_mfma(
    const unsigned short* __restrict__ Qb, const unsigned short* __restrict__ Kb,
    const unsigned short* __restrict__ Vt, unsigned short* __restrict__ ctxb,
    float* __restrict__ partO, float* __restrict__ partL)
{
    const int h = blockIdx.y;
    int qt, ch;
    {
        int x = blockIdx.x;
        if (x < 16) { qt = 16 + x; ch = 0; }
        else {
            int p = (x - 16) >> 1;
            if (((x - 16) & 1) == 0) { qt = 15 - p; ch = 0; }
            else                     { qt = 31 - p; ch = 1; }
        }
    }
    const int nch = (qt >= 16) ? 2 : 1;
    // units are BK=32 steps; a 1024-token chunk is 32 units. Always EVEN.
    const int units = (ch == 0) ? ((qt + 1 < 16) ? 2 * (qt + 1) : 32)
                                : (2 * (qt + 1) - 32);
    const int q0 = qt * BQ;
    const int kv = h >> 1;
    const int tid = threadIdx.x;
    const int w = tid >> 6;
    const int lane = tid & 63;
    const int col = lane & 15;
    const int quad = lane >> 4;

    __shared__ unsigned short Ks[2][32 * 128];   // 16 KB
    __shared__ unsigned short Vs[2][144 * 32];   // 18 KB (rows 128..143: ones/zeros)
    __shared__ unsigned short Ps[4][16][40];     // 5 KB (stride 40: 2-way banks)

    {
        int x = tid * 2;                          // ones region: 16 rows x 32 tok
        unsigned short vv = (x < 32) ? (unsigned short)0x3F80 : (unsigned short)0;
        ushort2 o = {vv, vv};
        *(ushort2*)&Vs[0][128 * 32 + x] = o;
        *(ushort2*)&Vs[1][128 * 32 + x] = o;
    }
    asm volatile("s_waitcnt lgkmcnt(0)" ::: "memory");  // ones visible pre-barrier

    short8 qf[4];
    {
        const unsigned short* qp = Qb + (size_t)(q0 + w * 16 + col) * Q_SIZE + h * HEAD_DIM;
        #pragma unroll
        for (int c = 0; c < 4; ++c)
            qf[c] = *(const short8*)(qp + c * 32 + quad * 8);
    }

    // Staging ptrs: K tile 32x128 = 512 chunks; V tile 128x32 = 512 chunks.
    const unsigned short* kg[2];
    const unsigned short* vg[2];
    #pragma unroll
    for (int it = 0; it < 2; ++it) {
        int s = it * 256 + tid;
        int kr = s >> 4, kp = s & 15, kj = kp ^ (kr & 15);
        kg[it] = Kb + (size_t)kv * T_SEQ * HEAD_DIM + kr * HEAD_DIM + kj * 8;
        int vr = s >> 2, vp = s & 3, vj = vp ^ ((vr >> 1) & 3);
        vg[it] = Vt + (size_t)kv * HEAD_DIM * T_SEQ + (size_t)vr * T_SEQ + vj * 8;
    }

    // ---- Hoisted per-thread LDS read bases (loop-invariant) ----
    const int kconst = col * 256;                         // bytes
    const char* k00 = (const char*)Ks[0] + kconst + (((0 * 4 + quad) ^ col) * 16);
    const char* k01 = (const char*)Ks[0] + kconst + (((1 * 4 + quad) ^ col) * 16);
    const char* k02 = (const char*)Ks[0] + kconst + (((2 * 4 + quad) ^ col) * 16);
    const char* k03 = (const char*)Ks[0] + kconst + (((3 * 4 + quad) ^ col) * 16);
    const char* k10 = (const char*)Ks[1] + kconst + (((0 * 4 + quad) ^ col) * 16);
    const char* k11 = (const char*)Ks[1] + kconst + (((1 * 4 + quad) ^ col) * 16);
    const char* k12 = (const char*)Ks[1] + kconst + (((2 * 4 + quad) ^ col) * 16);
    const char* k13 = (const char*)Ks[1] + kconst + (((3 * 4 + quad) ^ col) * 16);
    const int vconst = col * 64 + ((quad ^ ((col >> 1) & 3)) * 16);   // bytes
    const char* v0 = (const char*)Vs[0] + vconst;
    const char* v1 = (const char*)Vs[1] + vconst;
    char* psw = (char*)&Ps[w][col][quad * 4];             // write base (+cb*32 B)
    const char* psr = (const char*)&Ps[w][col][quad * 8]; // read base

    floatx4 Ob[9];
    #pragma unroll
    for (int cb = 0; cb < 9; ++cb) Ob[cb] = (floatx4){0.f, 0.f, 0.f, 0.f};

    const int wave_qmin = q0 + w * 16;
    const int wave_qmax = wave_qmin + 15;
    const int tok_base = ch * 1024;

    #pragma unroll
    for (int it = 0; it < 2; ++it) {
        stage16(kg[it] + (size_t)tok_base * HEAD_DIM, &Ks[0][(it * 256 + w * 64) * 8]);
        stage16(vg[it] + tok_base, &Vs[0][(it * 256 + w * 64) * 8]);
    }

    auto body = [&](int u, const char* kb0, const char* kb1, const char* kb2,
                    const char* kb3, const char* vb,
                    unsigned short* KsN, unsigned short* VsN) {
        const int t0 = tok_base + u * BK;
        if (u + 1 < units) {
            const int tn = t0 + BK;
            #pragma unroll
            for (int it = 0; it < 2; ++it) {
                stage16(kg[it] + (size_t)tn * HEAD_DIM, &KsN[(it * 256 + w * 64) * 8]);
                stage16(vg[it] + tn, &VsN[(it * 256 + w * 64) * 8]);
            }
            asm volatile("s_waitcnt vmcnt(4)" ::: "memory");   // tile u ready
        } else {
            asm volatile("s_waitcnt vmcnt(0)" ::: "memory");
        }
        __builtin_amdgcn_s_barrier();          // raw: prefetch stays in flight
        __builtin_amdgcn_sched_barrier(0);

        if (t0 <= wave_qmax) {
            floatx4 S[2];
            #pragma unroll
            for (int cb = 0; cb < 2; ++cb) {
                floatx4 a = (floatx4){0.f, 0.f, 0.f, 0.f};
                a = __builtin_amdgcn_mfma_f32_16x16x32_bf16(*(const short8*)(kb0 + cb * 4096), qf[0], a, 0, 0, 0);
                a = __builtin_amdgcn_mfma_f32_16x16x32_bf16(*(const short8*)(kb1 + cb * 4096), qf[1], a, 0, 0, 0);
                a = __builtin_amdgcn_mfma_f32_16x16x32_bf16(*(const short8*)(kb2 + cb * 4096), qf[2], a, 0, 0, 0);
                a = __builtin_amdgcn_mfma_f32_16x16x32_bf16(*(const short8*)(kb3 + cb * 4096), qf[3], a, 0, 0, 0);
                S[cb] = a;
            }

            const int qr = q0 + w * 16 + col;
            if (t0 + 31 <= wave_qmin) {
                #pragma unroll
                for (int cb = 0; cb < 2; ++cb) {
                    ushort4 pk;
                    pk.x = f2bf(__expf(S[cb][0])); pk.y = f2bf(__expf(S[cb][1]));
                    pk.z = f2bf(__expf(S[cb][2])); pk.w = f2bf(__expf(S[cb][3]));
                    *(ushort4*)(psw + cb * 32) = pk;
                }
            } else {
                #pragma unroll
                for (int cb = 0; cb < 2; ++cb) {
                    int kt = t0 + cb * 16 + quad * 4;
                    ushort4 pk;
                    pk.x = (kt + 0 <= qr) ? f2bf(__expf(S[cb][0])) : (unsigned short)0;
                    pk.y = (kt + 1 <= qr) ? f2bf(__expf(S[cb][1])) : (unsigned short)0;
                    pk.z = (kt + 2 <= qr) ? f2bf(__expf(S[cb][2])) : (unsigned short)0;
                    pk.w = (kt + 3 <= qr) ? f2bf(__expf(S[cb][3])) : (unsigned short)0;
                    *(ushort4*)(psw + cb * 32) = pk;
                }
            }

            short8 pf = *(const short8*)psr;
            #pragma unroll
            for (int cb = 0; cb < 9; ++cb)
                Ob[cb] = __builtin_amdgcn_mfma_f32_16x16x32_bf16(
                    pf, *(const short8*)(vb + cb * 1024), Ob[cb], 0, 0, 0);
        }
        __builtin_amdgcn_sched_barrier(0);
        asm volatile("" ::: "memory");
        __builtin_amdgcn_s_barrier();          // reads of this buf done before overwrite
    };

    for (int u = 0; u < units; u += 2) {
        body(u,     k00, k01, k02, k03, v0, Ks[1], Vs[1]);   // buf 0, prefetch -> 1
        body(u + 1, k10, k11, k12, k13, v1, Ks[0], Vs[0]);   // buf 1, prefetch -> 0
    }

    if (nch == 1) {
        #pragma unroll
        for (int r = 0; r < 4; ++r) {
            float l = __shfl(Ob[8][r], lane & 48);
            float rl = 1.0f / l;
            const int qrow = q0 + w * 16 + quad * 4 + r;
            #pragma unroll
            for (int cb = 0; cb < 8; ++cb)
                ctxb[(size_t)qrow * Q_SIZE + h * HEAD_DIM + cb * 16 + col] = f2bf(Ob[cb][r] * rl);
        }
    } else {
        const int slot = (h * 16 + (qt - 16)) * 2 + ch;
        float* po = partO + (size_t)slot * (BQ * HEAD_DIM);
        #pragma unroll
        for (int cb = 0; cb < 8; ++cb)
            #pragma unroll
            for (int r = 0; r < 4; ++r)
                po[(w * 16 + quad * 4 + r) * HEAD_DIM + cb * 16 + col] = Ob[cb][r];
        if (col == 0) {
            #pragma unroll
            for (int r = 0; r < 4; ++r)
                partL[slot * BQ + w * 16 + quad * 4 + r] = Ob[8][r];
        }
    }
}

// ---------------------------------------------------------------------------
// Combine: ctx[qt>=16] = (O0 + O1) / (l0 + l1).
// ---------------------------------------------------------------------------
__global__ __launch_bounds__(256) void combine(
    const float* __restrict__ partO, const float* __restrict__ partL,
    unsigned short* __restrict__ ctxb)
{
    const int h = blockIdx.x >> 4;
    const int qi = blockIdx.x & 15;
    const int q0 = (16 + qi) * 64;
    const int slot0 = (h * 16 + qi) * 2;
    const int tid = threadIdx.x;
    const int row = tid >> 2;
    const int seg = tid & 3;

    const float l = partL[slot0 * 64 + row] + partL[(slot0 + 1) * 64 + row];
    const float rl = 1.0f / l;
    const float* p0 = partO + (size_t)slot0 * 8192 + row * 128 + seg * 32;
    const float* p1 = p0 + 8192;
    unsigned short* dst = ctxb + (size_t)(q0 + row) * Q_SIZE + h * HEAD_DIM + seg * 32;
    #pragma unroll
    for (int m = 0; m < 8; ++m) {
        float4 a = *(const float4*)(p0 + m * 4);
        float4 b = *(const float4*)(p1 + m * 4);
        ushort4 o;
        o.x = f2bf((a.x + b.x) * rl); o.y = f2bf((a.y + b.y) * rl);
        o.z = f2bf((a.z + b.z) * rl); o.w = f2bf((a.w + b.w) * rl);
        *(ushort4*)(dst + m * 4) = o;
    }
}

// ---------------------------------------------------------------------------
extern "C" void kernel_launch(void* const* d_in, const int* in_sizes, int n_in,
                              void* d_out, int out_size, void* d_ws, size_t ws_size,
                              hipStream_t stream)
{
    const int*   positions = (const int*)d_in[0];
    const float* hidden    = (const float*)d_in[1];
    const float* qkv_w     = (const float*)d_in[2];
    const float* q_norm_w  = (const float*)d_in[3];
    const float* k_norm_w  = (const float*)d_in[4];
    const float* o_w       = (const float*)d_in[5];
    float* out = (float*)d_out;

    const size_t MB = 1024 * 1024;
    char* ws = (char*)d_ws;
    unsigned short* obf  = (unsigned short*)ws;                 // [0,8)   whole run
    unsigned short* hbf  = (unsigned short*)(ws + 8 * MB);      // [8,16)  dead after QKV GEMM
    unsigned short* wbf  = (unsigned short*)(ws + 16 * MB);     // [16,32) dead after QKV GEMM
    unsigned short* Vt   = (unsigned short*)(ws + 32 * MB);     // [32,36)
    unsigned short* Qb   = (unsigned short*)(ws + 36 * MB);     // [36,44)
    unsigned short* Kb   = (unsigned short*)(ws + 44 * MB);     // [44,48)
    unsigned short* ctxb = (unsigned short*)(ws + 48 * MB);     // [48,56)
    float* partL         = (float*)(ws + 8 * MB);               // [8,8.125) over dead hbf
    float* partO         = (float*)(ws + 16 * MB);              // [16,32) over dead wbf (16 MB)

    convert_all<<<(H4 + W4 + O4 + 255) / 256, 256, 0, stream>>>(
        hidden, qkv_w, o_w, hbf, wbf, obf);
    gemm_nt_bf16<1><<<dim3(QKV_N / 128, T_SEQ / 128), 1024, 0, stream>>>(
        hbf, wbf, nullptr, Qb, Kb, Vt, positions, q_norm_w, k_norm_w,
        T_SEQ, QKV_N, HIDDEN_);
    attn_mfma<<<dim3(48, NUM_HEADS), 256, 0, stream>>>(Qb, Kb, Vt, ctxb, partO, partL);
    combine<<<256, 256, 0, stream>>>(partO, partL, ctxb);
    gemm_nt_bf16<0><<<dim3(Q_SIZE / 128, T_SEQ / 128), 1024, 0, stream>>>(
        ctxb, obf, out, nullptr, nullptr, nullptr, nullptr, nullptr, nullptr,
        T_SEQ, Q_SIZE, HIDDEN_);
}